// Round 10
// baseline (456.308 us; speedup 1.0000x reference)
//
#include <hip/hip_runtime.h>

// Problem constants (fixed by the reference):
//   B=128 graphs, n=64 nodes/graph, E=65536 edges, K=16, D=64
//   e_full = B*n*n = 524288
#define EF      524288
#define NEDGE   65536
#define KDIM    16
#define DDIM    64
#define TPW     2      // 32-row tiles per wave in pv_gemm
#define PVBLK   (EF / (32 * TPW) / 4)   // 2048 true blocks
#define PVREP   3      // measurement: replicate grid 3x (idempotent rewrites)

typedef float vfloat4 __attribute__((ext_vector_type(4)));  // native vec for nontemporal
typedef short bf16x8  __attribute__((ext_vector_type(8)));  // 8 bf16 = 4 VGPR (MFMA A/B frag)
typedef float f32x16  __attribute__((ext_vector_type(16))); // MFMA C/D frag

__device__ __forceinline__ short f2bf(float f) {   // f32 -> bf16, round-to-nearest-even
    unsigned u = __float_as_uint(f);
    return (short)((u + 0x7FFFu + ((u >> 16) & 1u)) >> 16);
}

// ---------------------------------------------------------------------------
// Output 0: full_edge_index [2, EF], written as float32 values.
// ---------------------------------------------------------------------------
__global__ __launch_bounds__(256) void fill_idx(float* __restrict__ out) {
    int gid = blockIdx.x * 256 + threadIdx.x;      // 131072 threads, 4 j's each
    int j0 = gid << 2;
    vfloat4 rv, cv;
#pragma unroll
    for (int i = 0; i < 4; ++i) {
        int j = j0 + i;
        int g = j >> 12;
        int rem = j & 4095;
        rv[i] = (float)((g << 6) + (rem >> 6));
        cv[i] = (float)((g << 6) + (rem & 63));
    }
    __builtin_nontemporal_store(rv, reinterpret_cast<vfloat4*>(out + j0));
    __builtin_nontemporal_store(cv, reinterpret_cast<vfloat4*>(out + EF + j0));
}

// ---------------------------------------------------------------------------
// out_val = poly_val @ W^T via v_mfma_f32_32x32x16_bf16.
// v3 = v2 + NONTEMPORAL outv stores (128 MB pure stream; keep L2 clean).
// MEASUREMENT: grid is PVREP x PVBLK; bid & (PVBLK-1) makes replicas write
// identical bits to identical addresses (race-benign, deterministic) so the
// dispatch runs ~3x longer and surfaces in rocprof's top-5 with counters.
// ---------------------------------------------------------------------------
__global__ __launch_bounds__(256) void pv_gemm(const float* __restrict__ pv,
                                               const float* __restrict__ W,
                                               float* __restrict__ outv) {
    int bid = blockIdx.x & (PVBLK - 1);
    int tid = threadIdx.x;
    int wv  = tid >> 6;
    int l   = tid & 63;
    int n   = l & 31;               // within-tile pv row / D column index
    int kh  = l >> 5;               // k-half (0: k=0..7, 1: k=8..15)
    long j0 = ((long)bid * 4 + wv) * (32 * TPW);

    const float4* wp0 = reinterpret_cast<const float4*>(W + n * KDIM + kh * 8);
    const float4* wp1 = reinterpret_cast<const float4*>(W + (32 + n) * KDIM + kh * 8);
    float4 w0a = wp0[0], w0b = wp0[1], w1a = wp1[0], w1b = wp1[1];
    bf16x8 xa0, xa1;
    xa0[0]=f2bf(w0a.x); xa0[1]=f2bf(w0a.y); xa0[2]=f2bf(w0a.z); xa0[3]=f2bf(w0a.w);
    xa0[4]=f2bf(w0b.x); xa0[5]=f2bf(w0b.y); xa0[6]=f2bf(w0b.z); xa0[7]=f2bf(w0b.w);
    xa1[0]=f2bf(w1a.x); xa1[1]=f2bf(w1a.y); xa1[2]=f2bf(w1a.z); xa1[3]=f2bf(w1a.w);
    xa1[4]=f2bf(w1b.x); xa1[5]=f2bf(w1b.y); xa1[6]=f2bf(w1b.z); xa1[7]=f2bf(w1b.w);

#pragma unroll
    for (int t = 0; t < TPW; ++t) {
        long jt = j0 + t * 32;
        const float4* bp = reinterpret_cast<const float4*>(pv + (jt + n) * KDIM + kh * 8);
        float4 ba = bp[0], bb = bp[1];
        bf16x8 yf;
        yf[0]=f2bf(ba.x); yf[1]=f2bf(ba.y); yf[2]=f2bf(ba.z); yf[3]=f2bf(ba.w);
        yf[4]=f2bf(bb.x); yf[5]=f2bf(bb.y); yf[6]=f2bf(bb.z); yf[7]=f2bf(bb.w);

        f32x16 acc0 = {0,0,0,0, 0,0,0,0, 0,0,0,0, 0,0,0,0};
        f32x16 acc1 = {0,0,0,0, 0,0,0,0, 0,0,0,0, 0,0,0,0};
        acc0 = __builtin_amdgcn_mfma_f32_32x32x16_bf16(xa0, yf, acc0, 0, 0, 0);
        acc1 = __builtin_amdgcn_mfma_f32_32x32x16_bf16(xa1, yf, acc1, 0, 0, 0);

        float* base = outv + (jt + n) * DDIM + kh * 4;   // this lane's row
#pragma unroll
        for (int q = 0; q < 4; ++q) {
            vfloat4 s0 = {acc0[4*q], acc0[4*q+1], acc0[4*q+2], acc0[4*q+3]};
            vfloat4 s1 = {acc1[4*q], acc1[4*q+1], acc1[4*q+2], acc1[4*q+3]};
            __builtin_nontemporal_store(s0, reinterpret_cast<vfloat4*>(base + 8*q));
            __builtin_nontemporal_store(s1, reinterpret_cast<vfloat4*>(base + 8*q + 32));
        }
    }
}

// ---------------------------------------------------------------------------
// Scatter, dedup-RMW (unchanged from R9 for clean subtraction).
// ---------------------------------------------------------------------------
__global__ __launch_bounds__(256) void zero_cnt(unsigned* __restrict__ cnt) {
    int gid = blockIdx.x * 256 + threadIdx.x;
    reinterpret_cast<uint4*>(cnt)[gid] = make_uint4(0, 0, 0, 0);   // 16 B/thread
}

__device__ __forceinline__ long edge_slot(const int* ei, int e) {
    int r = ei[e];
    int c = ei[NEDGE + e];
    return ((long)(r >> 6) << 12) + ((long)(r & 63) << 6) + (long)(c & 63);
}

__global__ __launch_bounds__(256) void count_edges(const int* __restrict__ ei,
                                                   unsigned* __restrict__ cnt) {
    int e = blockIdx.x * 256 + threadIdx.x;        // NEDGE threads
    atomicAdd(&cnt[edge_slot(ei, e)], 1u);
}

__global__ __launch_bounds__(256) void scatter2(const float* __restrict__ ea,
                                                const int* __restrict__ ei,
                                                const unsigned* __restrict__ cnt,
                                                float* __restrict__ outv) {
    int gid = blockIdx.x * 256 + threadIdx.x;      // NEDGE*16 threads
    int e = gid >> 4;
    int t = gid & 15;
    long slot = edge_slot(ei, e);
    float4 v = *reinterpret_cast<const float4*>(ea + (long)e * DDIM + t * 4);
    float* dst = outv + slot * DDIM + t * 4;
    if (cnt[slot] == 1u) {                          // exclusive slot: plain RMW
        float4 o = *reinterpret_cast<const float4*>(dst);
        o.x += v.x; o.y += v.y; o.z += v.z; o.w += v.w;
        *reinterpret_cast<float4*>(dst) = o;
    } else {                                        // collision: atomic
        unsafeAtomicAdd(dst + 0, v.x);
        unsafeAtomicAdd(dst + 1, v.y);
        unsafeAtomicAdd(dst + 2, v.z);
        unsafeAtomicAdd(dst + 3, v.w);
    }
}

// Fallback (ws too small): original all-atomic scatter.
__global__ __launch_bounds__(256) void scatter_edges(const float* __restrict__ ea,
                                                     const int* __restrict__ ei,
                                                     float* __restrict__ outv) {
    int gid = blockIdx.x * 256 + threadIdx.x;
    int e = gid >> 4;
    int t = gid & 15;
    long slot = edge_slot(ei, e);
    float4 v = *reinterpret_cast<const float4*>(ea + (long)e * DDIM + t * 4);
    float* dst = outv + slot * DDIM + t * 4;
    unsafeAtomicAdd(dst + 0, v.x);
    unsafeAtomicAdd(dst + 1, v.y);
    unsafeAtomicAdd(dst + 2, v.z);
    unsafeAtomicAdd(dst + 3, v.w);
}

extern "C" void kernel_launch(void* const* d_in, const int* in_sizes, int n_in,
                              void* d_out, int out_size, void* d_ws, size_t ws_size,
                              hipStream_t stream) {
    const float* poly_val  = (const float*)d_in[0];   // [EF, 16]
    const float* edge_attr = (const float*)d_in[1];   // [NEDGE, 64]
    const float* W         = (const float*)d_in[2];   // [64, 16]
    // d_in[3] = poly_idx (identity slot order -> unused)
    const int*   edge_index = (const int*)d_in[4];    // [2, NEDGE]
    // d_in[5] = batch, d_in[6] = num_graphs (unused; constants fixed)

    float* out  = (float*)d_out;          // [2*EF] indices as f32, then out_val
    float* outv = out + 2 * (long)EF;     // [EF, 64]

    fill_idx<<<EF / 4 / 256, 256, 0, stream>>>(out);
    pv_gemm<<<PVREP * PVBLK, 256, 0, stream>>>(poly_val, W, outv);  // 3x replicated (measurement)

    if (ws_size >= (size_t)EF * sizeof(unsigned)) {
        unsigned* cnt = (unsigned*)d_ws;
        zero_cnt<<<EF / 4 / 256, 256, 0, stream>>>(cnt);
        count_edges<<<NEDGE / 256, 256, 0, stream>>>(edge_index, cnt);
        scatter2<<<(NEDGE * 16) / 256, 256, 0, stream>>>(edge_attr, edge_index, cnt, outv);
    } else {
        scatter_edges<<<(NEDGE * 16) / 256, 256, 0, stream>>>(edge_attr, edge_index, outv);
    }
}

// Round 11
// 57.195 us; speedup vs baseline: 7.9781x; 7.9781x over previous
//
#include <hip/hip_runtime.h>

// Problem constants (fixed by the reference):
//   B=128 graphs, n=64 nodes/graph, E=65536 edges, K=16, D=64
//   e_full = B*n*n = 524288
#define EF      524288
#define NEDGE   65536
#define KDIM    16
#define DDIM    64
#define TPW     2      // 32-row tiles per wave in pv_gemm
#define PVBLK   (EF / (32 * TPW) / 4)   // 2048 blocks, 4 waves each
#define LSTR    68     // LDS row stride in floats (16B-aligned, spreads banks)

typedef float vfloat4 __attribute__((ext_vector_type(4)));  // native vec for nontemporal
typedef short bf16x8  __attribute__((ext_vector_type(8)));  // 8 bf16 = 4 VGPR (MFMA A/B frag)
typedef float f32x16  __attribute__((ext_vector_type(16))); // MFMA C/D frag

__device__ __forceinline__ short f2bf(float f) {   // f32 -> bf16, round-to-nearest-even
    unsigned u = __float_as_uint(f);
    return (short)((u + 0x7FFFu + ((u >> 16) & 1u)) >> 16);
}

// ---------------------------------------------------------------------------
// Output 0: full_edge_index [2, EF], written as float32 values.
// ---------------------------------------------------------------------------
__global__ __launch_bounds__(256) void fill_idx(float* __restrict__ out) {
    int gid = blockIdx.x * 256 + threadIdx.x;      // 131072 threads, 4 j's each
    int j0 = gid << 2;
    vfloat4 rv, cv;
#pragma unroll
    for (int i = 0; i < 4; ++i) {
        int j = j0 + i;
        int g = j >> 12;
        int rem = j & 4095;
        rv[i] = (float)((g << 6) + (rem >> 6));
        cv[i] = (float)((g << 6) + (rem & 63));
    }
    __builtin_nontemporal_store(rv, reinterpret_cast<vfloat4*>(out + j0));
    __builtin_nontemporal_store(cv, reinterpret_cast<vfloat4*>(out + EF + j0));
}

// ---------------------------------------------------------------------------
// out_val = poly_val @ W^T via v_mfma_f32_32x32x16_bf16.
// v4: per-wave LDS transpose of the C tile so global stores are DENSE.
// R10 profile showed the MFMA-layout stores (16B/lane across 32 rows at
// 256B stride) caused ~2.2x HBM write amplification under nontemporal.
// Now: acc -> LDS (row stride 68 floats, ~bank-floor) -> linear readback ->
// each global store instr = 64 lanes x 16B = 1KB contiguous full lines,
// which makes nontemporal safe (no partial-line eviction).
// Same-wave LDS write->read needs no barrier (compiler emits lgkmcnt).
// ---------------------------------------------------------------------------
__global__ __launch_bounds__(256) void pv_gemm(const float* __restrict__ pv,
                                               const float* __restrict__ W,
                                               float* __restrict__ outv) {
    __shared__ float lds[4][32 * LSTR];   // 34.8 KB, private region per wave
    int tid = threadIdx.x;
    int wv  = tid >> 6;
    int l   = tid & 63;
    int n   = l & 31;               // within-tile pv row
    int kh  = l >> 5;               // k-half (0: k=0..7, 1: k=8..15)
    long j0 = ((long)blockIdx.x * 4 + wv) * (32 * TPW);

    const float4* wp0 = reinterpret_cast<const float4*>(W + n * KDIM + kh * 8);
    const float4* wp1 = reinterpret_cast<const float4*>(W + (32 + n) * KDIM + kh * 8);
    float4 w0a = wp0[0], w0b = wp0[1], w1a = wp1[0], w1b = wp1[1];
    bf16x8 xa0, xa1;
    xa0[0]=f2bf(w0a.x); xa0[1]=f2bf(w0a.y); xa0[2]=f2bf(w0a.z); xa0[3]=f2bf(w0a.w);
    xa0[4]=f2bf(w0b.x); xa0[5]=f2bf(w0b.y); xa0[6]=f2bf(w0b.z); xa0[7]=f2bf(w0b.w);
    xa1[0]=f2bf(w1a.x); xa1[1]=f2bf(w1a.y); xa1[2]=f2bf(w1a.z); xa1[3]=f2bf(w1a.w);
    xa1[4]=f2bf(w1b.x); xa1[5]=f2bf(w1b.y); xa1[6]=f2bf(w1b.z); xa1[7]=f2bf(w1b.w);

    float* myl = lds[wv];

#pragma unroll
    for (int t = 0; t < TPW; ++t) {
        long jt = j0 + t * 32;
        const float4* bp = reinterpret_cast<const float4*>(pv + (jt + n) * KDIM + kh * 8);
        float4 ba = bp[0], bb = bp[1];
        bf16x8 yf;
        yf[0]=f2bf(ba.x); yf[1]=f2bf(ba.y); yf[2]=f2bf(ba.z); yf[3]=f2bf(ba.w);
        yf[4]=f2bf(bb.x); yf[5]=f2bf(bb.y); yf[6]=f2bf(bb.z); yf[7]=f2bf(bb.w);

        f32x16 acc0 = {0,0,0,0, 0,0,0,0, 0,0,0,0, 0,0,0,0};
        f32x16 acc1 = {0,0,0,0, 0,0,0,0, 0,0,0,0, 0,0,0,0};
        acc0 = __builtin_amdgcn_mfma_f32_32x32x16_bf16(xa0, yf, acc0, 0, 0, 0);
        acc1 = __builtin_amdgcn_mfma_f32_32x32x16_bf16(xa1, yf, acc1, 0, 0, 0);

        // acc -> LDS: lane (n,kh), reg 4q+i holds C[n][8q+4kh+i] (acc0),
        // C[n][32+8q+4kh+i] (acc1).
#pragma unroll
        for (int q = 0; q < 4; ++q) {
            vfloat4 s0 = {acc0[4*q], acc0[4*q+1], acc0[4*q+2], acc0[4*q+3]};
            vfloat4 s1 = {acc1[4*q], acc1[4*q+1], acc1[4*q+2], acc1[4*q+3]};
            *reinterpret_cast<vfloat4*>(myl + n * LSTR + 8*q + 4*kh)      = s0;
            *reinterpret_cast<vfloat4*>(myl + n * LSTR + 32 + 8*q + 4*kh) = s1;
        }

        // LDS -> global, linear: instr i covers rows 4i..4i+3 fully (1KB).
#pragma unroll
        for (int i = 0; i < 8; ++i) {
            int row  = 4*i + (l >> 4);
            int colf = (l & 15) * 4;
            vfloat4 v = *reinterpret_cast<const vfloat4*>(myl + row * LSTR + colf);
            __builtin_nontemporal_store(v,
                reinterpret_cast<vfloat4*>(outv + (jt + row) * DDIM + colf));
        }
    }
}

// ---------------------------------------------------------------------------
// Scatter, dedup-RMW (unchanged from R9).
// ---------------------------------------------------------------------------
__global__ __launch_bounds__(256) void zero_cnt(unsigned* __restrict__ cnt) {
    int gid = blockIdx.x * 256 + threadIdx.x;
    reinterpret_cast<uint4*>(cnt)[gid] = make_uint4(0, 0, 0, 0);   // 16 B/thread
}

__device__ __forceinline__ long edge_slot(const int* ei, int e) {
    int r = ei[e];
    int c = ei[NEDGE + e];
    return ((long)(r >> 6) << 12) + ((long)(r & 63) << 6) + (long)(c & 63);
}

__global__ __launch_bounds__(256) void count_edges(const int* __restrict__ ei,
                                                   unsigned* __restrict__ cnt) {
    int e = blockIdx.x * 256 + threadIdx.x;        // NEDGE threads
    atomicAdd(&cnt[edge_slot(ei, e)], 1u);
}

__global__ __launch_bounds__(256) void scatter2(const float* __restrict__ ea,
                                                const int* __restrict__ ei,
                                                const unsigned* __restrict__ cnt,
                                                float* __restrict__ outv) {
    int gid = blockIdx.x * 256 + threadIdx.x;      // NEDGE*16 threads
    int e = gid >> 4;
    int t = gid & 15;
    long slot = edge_slot(ei, e);
    float4 v = *reinterpret_cast<const float4*>(ea + (long)e * DDIM + t * 4);
    float* dst = outv + slot * DDIM + t * 4;
    if (cnt[slot] == 1u) {                          // exclusive slot: plain RMW
        float4 o = *reinterpret_cast<const float4*>(dst);
        o.x += v.x; o.y += v.y; o.z += v.z; o.w += v.w;
        *reinterpret_cast<float4*>(dst) = o;
    } else {                                        // collision: atomic
        unsafeAtomicAdd(dst + 0, v.x);
        unsafeAtomicAdd(dst + 1, v.y);
        unsafeAtomicAdd(dst + 2, v.z);
        unsafeAtomicAdd(dst + 3, v.w);
    }
}

// Fallback (ws too small): original all-atomic scatter.
__global__ __launch_bounds__(256) void scatter_edges(const float* __restrict__ ea,
                                                     const int* __restrict__ ei,
                                                     float* __restrict__ outv) {
    int gid = blockIdx.x * 256 + threadIdx.x;
    int e = gid >> 4;
    int t = gid & 15;
    long slot = edge_slot(ei, e);
    float4 v = *reinterpret_cast<const float4*>(ea + (long)e * DDIM + t * 4);
    float* dst = outv + slot * DDIM + t * 4;
    unsafeAtomicAdd(dst + 0, v.x);
    unsafeAtomicAdd(dst + 1, v.y);
    unsafeAtomicAdd(dst + 2, v.z);
    unsafeAtomicAdd(dst + 3, v.w);
}

extern "C" void kernel_launch(void* const* d_in, const int* in_sizes, int n_in,
                              void* d_out, int out_size, void* d_ws, size_t ws_size,
                              hipStream_t stream) {
    const float* poly_val  = (const float*)d_in[0];   // [EF, 16]
    const float* edge_attr = (const float*)d_in[1];   // [NEDGE, 64]
    const float* W         = (const float*)d_in[2];   // [64, 16]
    // d_in[3] = poly_idx (identity slot order -> unused)
    const int*   edge_index = (const int*)d_in[4];    // [2, NEDGE]
    // d_in[5] = batch, d_in[6] = num_graphs (unused; constants fixed)

    float* out  = (float*)d_out;          // [2*EF] indices as f32, then out_val
    float* outv = out + 2 * (long)EF;     // [EF, 64]

    fill_idx<<<EF / 4 / 256, 256, 0, stream>>>(out);
    pv_gemm<<<PVBLK, 256, 0, stream>>>(poly_val, W, outv);

    if (ws_size >= (size_t)EF * sizeof(unsigned)) {
        unsigned* cnt = (unsigned*)d_ws;
        zero_cnt<<<EF / 4 / 256, 256, 0, stream>>>(cnt);
        count_edges<<<NEDGE / 256, 256, 0, stream>>>(edge_index, cnt);
        scatter2<<<(NEDGE * 16) / 256, 256, 0, stream>>>(edge_attr, edge_index, cnt, outv);
    } else {
        scatter_edges<<<(NEDGE * 16) / 256, 256, 0, stream>>>(edge_attr, edge_index, outv);
    }
}